// Round 1
// baseline (120.426 us; speedup 1.0000x reference)
//
#include <hip/hip_runtime.h>

#define BEVN 100
#define NB 8
#define NC 512
#define FH 88
#define FW 176
#define HWSZ (FH * FW)   // 15488 floats = 61,952 B per (b,c) slice

// One block per (b,c) channel slice. Stage the slice in LDS, then each thread
// evaluates ~10 BEV cells (3 height planes x bilinear) out of registers/LDS.
__global__ __launch_bounds__(1024, 8)
void vt_kernel(const float* __restrict__ img,
               const float* __restrict__ intr,
               const int* __restrict__ p_imw,
               const int* __restrict__ p_imh,
               float* __restrict__ out)
{
    __shared__ float lds[HWSZ];

    const int bc = blockIdx.x;          // b*512 + c
    const int b  = bc >> 9;

    // ---- stage [88][176] f32 slice into LDS, coalesced float4 ----
    {
        const float4* __restrict__ s4 = (const float4*)(img + (size_t)bc * HWSZ);
        float4* l4 = (float4*)lds;
        #pragma unroll
        for (int t = 0; t < 4; ++t) {
            const int idx = (int)threadIdx.x + t * 1024;
            if (idx < HWSZ / 4) l4[idx] = s4[idx];
        }
    }

    // intrinsics for this batch
    const float fx  = intr[b * 9 + 0];
    const float cxv = intr[b * 9 + 2];
    const float fy  = intr[b * 9 + 4];
    const float cyv = intr[b * 9 + 5];
    // feature/image scale: x_pix = (fx*xz + cx) * (FW/img_w) - 0.5 (align_corners=False)
    const float wsc = (float)FW / (float)p_imw[0];   // 0.25
    const float hsc = (float)FH / (float)p_imh[0];   // 0.25

    __syncthreads();

    float* __restrict__ op = out + (size_t)bc * (BEVN * BEVN);

    for (int cell = (int)threadIdx.x; cell < BEVN * BEVN; cell += 1024) {
        const int i = cell / BEVN;          // z index (row)
        const int j = cell - i * BEVN;      // x index (col)

        const float z    = 0.125f + 0.5f * (float)i;
        const float invz = 1.0f / z;
        const float xw   = -24.875f + 0.5f * (float)j;

        // shared-by-all-planes x pixel coordinate
        const float xpix = (fx * (xw * invz) + cxv) * wsc - 0.5f;
        const float x0f  = floorf(xpix);
        const int   x0   = (int)x0f;
        const float wx1  = xpix - x0f;
        const float wx0  = 1.0f - wx1;
        const bool  vx0  = (x0 >= 0) && (x0 < FW);
        const bool  vx1  = (x0 >= -1) && (x0 < FW - 1);

        float acc = 0.0f;
        if (vx0 || vx1) {
            const int xc0 = min(max(x0, 0), FW - 1);
            const int xc1 = min(max(x0 + 1, 0), FW - 1);
            #pragma unroll
            for (int k = 0; k < 3; ++k) {
                const float yk   = (k == 0) ? -1.0f : ((k == 1) ? 0.5f : 2.0f);
                const float ypix = (fy * (yk * invz) + cyv) * hsc - 0.5f;
                const float y0f  = floorf(ypix);
                const int   y0   = (int)y0f;
                const float wy1  = ypix - y0f;
                const float wy0  = 1.0f - wy1;
                const bool  vy0  = (y0 >= 0) && (y0 < FH);
                const bool  vy1  = (y0 >= -1) && (y0 < FH - 1);
                if (vy0 | vy1) {
                    const int yb0 = min(max(y0, 0), FH - 1) * FW;
                    const int yb1 = min(max(y0 + 1, 0), FH - 1) * FW;
                    const float v00 = (vy0 && vx0) ? lds[yb0 + xc0] : 0.0f;
                    const float v01 = (vy0 && vx1) ? lds[yb0 + xc1] : 0.0f;
                    const float v10 = (vy1 && vx0) ? lds[yb1 + xc0] : 0.0f;
                    const float v11 = (vy1 && vx1) ? lds[yb1 + xc1] : 0.0f;
                    acc += wy0 * (wx0 * v00 + wx1 * v01)
                         + wy1 * (wx0 * v10 + wx1 * v11);
                }
            }
        }
        op[cell] = acc * (1.0f / 3.0f);
    }
}

extern "C" void kernel_launch(void* const* d_in, const int* in_sizes, int n_in,
                              void* d_out, int out_size, void* d_ws, size_t ws_size,
                              hipStream_t stream) {
    const float* img  = (const float*)d_in[0];
    const float* intr = (const float*)d_in[1];
    const int*   imw  = (const int*)d_in[2];
    const int*   imh  = (const int*)d_in[3];
    float*       out  = (float*)d_out;

    dim3 grid(NB * NC);   // one block per (b,c)
    dim3 block(1024);
    hipLaunchKernelGGL(vt_kernel, grid, block, 0, stream,
                       img, intr, imw, imh, out);
}

// Round 2
// 90.805 us; speedup vs baseline: 1.3262x; 1.3262x over previous
//
#include <hip/hip_runtime.h>

#define BEVN 100
#define NB 8
#define NC 512
#define FH 88
#define FW 176
#define HWSZ (FH * FW)          // 15488 floats = 61,952 B per (b,c) slice
#define NPAIR (BEVN * BEVN / 2) // 5000 cell-pairs per slice

// One block per (b,c). Stage slice in LDS + per-row y-projection table
// (validity & 1/3 folded into weights). Each thread handles cell PAIRS
// (pairs never straddle rows: 100 is even), sharing invz + y-table reads,
// and writes float2.
__global__ __launch_bounds__(1024, 8)
void vt_kernel(const float* __restrict__ img,
               const float* __restrict__ intr,
               const int* __restrict__ p_imw,
               const int* __restrict__ p_imh,
               float* __restrict__ out)
{
    __shared__ float  lds[HWSZ];
    __shared__ float4 ytab[BEVN * 3];   // per (row,plane): {wy0/3, wy1/3, rowbase0, rowbase1}

    const int bc  = blockIdx.x;         // b*512 + c
    const int b   = bc >> 9;
    const int tid = (int)threadIdx.x;

    // ---- stage [88][176] f32 slice into LDS, coalesced float4 ----
    {
        const float4* __restrict__ s4 = (const float4*)(img + (size_t)bc * HWSZ);
        float4* l4 = (float4*)lds;
        #pragma unroll
        for (int t = 0; t < 4; ++t) {
            const int idx = tid + t * 1024;
            if (idx < HWSZ / 4) l4[idx] = s4[idx];
        }
    }

    const float fx  = intr[b * 9 + 0];
    const float cxv = intr[b * 9 + 2];
    const float fy  = intr[b * 9 + 4];
    const float cyv = intr[b * 9 + 5];
    const float wsc = (float)FW / (float)p_imw[0];   // 0.25
    const float hsc = (float)FH / (float)p_imh[0];   // 0.25

    // ---- per-row y table: depends only on (b, row, plane). 300 entries ----
    if (tid < BEVN * 3) {
        const int   i  = tid / 3;
        const int   k  = tid - 3 * i;
        const float z  = 0.125f + 0.5f * (float)i;
        const float iz = 1.0f / z;                    // precise, one-time
        const float yk = (k == 0) ? -1.0f : ((k == 1) ? 0.5f : 2.0f);
        const float yp = fmaf(fy * yk * iz + cyv, hsc, -0.5f);
        const float yf = floorf(yp);
        const int   y0 = (int)yf;
        float wy1 = yp - yf;
        float wy0 = 1.0f - wy1;
        wy0 = ((unsigned)y0 < (unsigned)FH) ? wy0 : 0.0f;
        wy1 = ((unsigned)(y0 + 1) < (unsigned)FH) ? wy1 : 0.0f;
        const int yb0 = min(max(y0, 0), FH - 1) * FW;
        const int yb1 = min(max(y0 + 1, 0), FH - 1) * FW;
        float4 e;
        e.x = wy0 * (1.0f / 3.0f);
        e.y = wy1 * (1.0f / 3.0f);
        e.z = __int_as_float(yb0);
        e.w = __int_as_float(yb1);
        ytab[tid] = e;
    }

    __syncthreads();

    // x-projection constants: xpix = a_j * invz + bx, a_j = axb + axs*j
    const float axs = 0.5f * fx * wsc;
    const float axb = -24.875f * fx * wsc;
    const float bx  = fmaf(cxv, wsc, -0.5f);

    float* __restrict__ op = out + (size_t)bc * (BEVN * BEVN);

    for (int p = tid; p < NPAIR; p += 1024) {
        const int i  = p / 50;               // BEV row
        const int jp = p - 50 * i;           // pair index in row
        const float z    = fmaf(0.5f, (float)i, 0.125f);
        const float invz = __builtin_amdgcn_rcpf(z);

        const float aj0 = fmaf((float)(2 * jp), axs, axb);
        const float aj1 = aj0 + axs;

        // ---- x side, element 0 ----
        const float xp0 = fmaf(aj0, invz, bx);
        const float f0  = floorf(xp0);
        const int   x00 = (int)f0;
        float wx1_0 = xp0 - f0;
        float wx0_0 = 1.0f - wx1_0;
        wx0_0 = ((unsigned)x00 < (unsigned)FW) ? wx0_0 : 0.0f;
        wx1_0 = ((unsigned)(x00 + 1) < (unsigned)FW) ? wx1_0 : 0.0f;
        const int xc0_0 = min(max(x00, 0), FW - 1);
        const int xc1_0 = min(max(x00 + 1, 0), FW - 1);

        // ---- x side, element 1 ----
        const float xp1 = fmaf(aj1, invz, bx);
        const float f1  = floorf(xp1);
        const int   x01 = (int)f1;
        float wx1_1 = xp1 - f1;
        float wx0_1 = 1.0f - wx1_1;
        wx0_1 = ((unsigned)x01 < (unsigned)FW) ? wx0_1 : 0.0f;
        wx1_1 = ((unsigned)(x01 + 1) < (unsigned)FW) ? wx1_1 : 0.0f;
        const int xc0_1 = min(max(x01, 0), FW - 1);
        const int xc1_1 = min(max(x01 + 1, 0), FW - 1);

        float2 res;
        if ((wx0_0 + wx1_0 + wx0_1 + wx1_1) == 0.0f) {
            // whole pair outside the image in x -> zero (wave-coherent skip)
            res.x = 0.0f; res.y = 0.0f;
        } else {
            float acc0 = 0.0f, acc1 = 0.0f;
            #pragma unroll
            for (int k = 0; k < 3; ++k) {
                const float4 e  = ytab[i * 3 + k];
                const int   yb0 = __float_as_int(e.z);
                const int   yb1 = __float_as_int(e.w);
                // element 0
                {
                    const float v00 = lds[yb0 + xc0_0];
                    const float v01 = lds[yb0 + xc1_0];
                    const float v10 = lds[yb1 + xc0_0];
                    const float v11 = lds[yb1 + xc1_0];
                    const float h0 = fmaf(wx1_0, v01, wx0_0 * v00);
                    const float h1 = fmaf(wx1_0, v11, wx0_0 * v10);
                    acc0 = fmaf(e.x, h0, acc0);
                    acc0 = fmaf(e.y, h1, acc0);
                }
                // element 1
                {
                    const float v00 = lds[yb0 + xc0_1];
                    const float v01 = lds[yb0 + xc1_1];
                    const float v10 = lds[yb1 + xc0_1];
                    const float v11 = lds[yb1 + xc1_1];
                    const float h0 = fmaf(wx1_1, v01, wx0_1 * v00);
                    const float h1 = fmaf(wx1_1, v11, wx0_1 * v10);
                    acc1 = fmaf(e.x, h0, acc1);
                    acc1 = fmaf(e.y, h1, acc1);
                }
            }
            res.x = acc0; res.y = acc1;    // 1/3 already folded into e.x/e.y
        }
        *(float2*)(op + 2 * p) = res;
    }
}

extern "C" void kernel_launch(void* const* d_in, const int* in_sizes, int n_in,
                              void* d_out, int out_size, void* d_ws, size_t ws_size,
                              hipStream_t stream) {
    const float* img  = (const float*)d_in[0];
    const float* intr = (const float*)d_in[1];
    const int*   imw  = (const int*)d_in[2];
    const int*   imh  = (const int*)d_in[3];
    float*       out  = (float*)d_out;

    dim3 grid(NB * NC);   // one block per (b,c)
    dim3 block(1024);
    hipLaunchKernelGGL(vt_kernel, grid, block, 0, stream,
                       img, intr, imw, imh, out);
}